// Round 1
// baseline (805.209 us; speedup 1.0000x reference)
//
#include <hip/hip_runtime.h>

typedef __attribute__((ext_vector_type(8))) short bf16x8;
typedef __attribute__((ext_vector_type(4))) float f32x4;
typedef __attribute__((ext_vector_type(4))) short s16x4;

#define DEV static __device__ __forceinline__

constexpr int B_ = 2, H_ = 16, L_ = 2048, D_ = 64;
constexpr float SCALE = 0.125f;  // 1/sqrt(64)

DEV short f2bf(float f) {
  unsigned u = __builtin_bit_cast(unsigned, f);
  u += 0x7fffu + ((u >> 16) & 1u);  // RNE
  return (short)(u >> 16);
}

// ---------------- Kernel 1: P = softmax(QK^T * scale * mask) ----------------
// grid: B*H*(L/32) blocks of 512 threads (8 waves: 2 row-groups x 4 col-groups)
// Each wave: 16 q-rows x 512 k-cols of logits in 32 MFMA accum frags (128 VGPR).
__global__ __launch_bounds__(512, 2) void qk_softmax_kernel(
    const float* __restrict__ Qg, const float* __restrict__ Kg,
    const float* __restrict__ Mg, float* __restrict__ Pg) {
  const int tid = threadIdx.x;
  const int w = tid >> 6, lane = tid & 63;
  const int g = lane >> 4, ln = lane & 15;
  const int wr = w >> 2, wc = w & 3;

  const int nq = L_ / 32;  // 64 q-tiles
  const int blk = blockIdx.x;
  const int q0 = (blk % nq) * 32;
  const int bh = blk / nq;
  const int b = bh >> 4;  // H_=16

  const float* q = Qg + (size_t)bh * L_ * D_;
  const float* k = Kg + (size_t)bh * L_ * D_;
  const float* m = Mg + (size_t)b * L_ * L_;
  float* p = Pg + (size_t)bh * L_ * L_;

  __shared__ short kt_lds[64 * 64];  // 8KB bf16, XOR-swizzled rows of 128B
  __shared__ float red_m[8][32];
  __shared__ float red_s[8][32];

  // A frags (Q rows q0 + wr*16 + ln), held for whole kernel. slot map: d = half*32 + g*8 + e
  bf16x8 a[2];
  {
    const float* qr = q + (size_t)(q0 + wr * 16 + ln) * D_ + g * 8;
#pragma unroll
    for (int hh = 0; hh < 2; ++hh) {
      float4 f0 = *(const float4*)(qr + hh * 32);
      float4 f1 = *(const float4*)(qr + hh * 32 + 4);
      a[hh][0] = f2bf(f0.x); a[hh][1] = f2bf(f0.y);
      a[hh][2] = f2bf(f0.z); a[hh][3] = f2bf(f0.w);
      a[hh][4] = f2bf(f1.x); a[hh][5] = f2bf(f1.y);
      a[hh][6] = f2bf(f1.z); a[hh][7] = f2bf(f1.w);
    }
  }

  f32x4 acc[32];
#pragma unroll
  for (int i = 0; i < 32; ++i) acc[i] = f32x4{0.f, 0.f, 0.f, 0.f};

  const int br = wc * 16 + ln;        // K row within tile for this lane's B-frag
  const int bswz = (br & 7) << 4;

#pragma unroll
  for (int kt = 0; kt < 32; ++kt) {
    __syncthreads();
    // stage K tile [64 k][64 d] -> bf16, swizzle byte ^= (row&7)<<4
#pragma unroll
    for (int it = 0; it < 2; ++it) {
      int idx = it * 512 + tid;        // float4 index, 1024 total
      int r = idx >> 4, c4 = idx & 15;
      float4 vv = *(const float4*)(k + (size_t)(kt * 64 + r) * D_ + c4 * 4);
      s16x4 s;
      s[0] = f2bf(vv.x); s[1] = f2bf(vv.y); s[2] = f2bf(vv.z); s[3] = f2bf(vv.w);
      *(s16x4*)((char*)kt_lds + r * 128 + ((c4 * 8) ^ ((r & 7) << 4))) = s;
    }
    __syncthreads();
    // B frags: same (g,e)->d slot map as A, so contraction order is consistent
    bf16x8 b0 = *(const bf16x8*)((const char*)kt_lds + br * 128 + ((g * 16) ^ bswz));
    bf16x8 b1 = *(const bf16x8*)((const char*)kt_lds + br * 128 + ((64 + g * 16) ^ bswz));
    acc[kt] = __builtin_amdgcn_mfma_f32_16x16x32_bf16(a[0], b0, acc[kt], 0, 0, 0);
    acc[kt] = __builtin_amdgcn_mfma_f32_16x16x32_bf16(a[1], b1, acc[kt], 0, 0, 0);
  }

  // ---- softmax over k (C/D layout: col = ln -> k-pos, row = g*4+reg -> q-row) ----
  const int row_base = q0 + wr * 16 + g * 4;
  float mx[4] = {-1e30f, -1e30f, -1e30f, -1e30f};
#pragma unroll
  for (int kt = 0; kt < 32; ++kt) {
    const int col = kt * 64 + wc * 16 + ln;
#pragma unroll
    for (int r = 0; r < 4; ++r) {
      float lg = acc[kt][r] * SCALE * m[(size_t)(row_base + r) * L_ + col];
      acc[kt][r] = lg;
      mx[r] = fmaxf(mx[r], lg);
    }
  }
#pragma unroll
  for (int r = 0; r < 4; ++r) {  // reduce across the 16 lanes sharing a row
    float vv = mx[r];
    vv = fmaxf(vv, __shfl_xor(vv, 1));
    vv = fmaxf(vv, __shfl_xor(vv, 2));
    vv = fmaxf(vv, __shfl_xor(vv, 4));
    vv = fmaxf(vv, __shfl_xor(vv, 8));
    mx[r] = vv;
  }
  if (ln == 0) {
#pragma unroll
    for (int r = 0; r < 4; ++r) red_m[w][g * 4 + r] = mx[r];
  }
  __syncthreads();
#pragma unroll
  for (int r = 0; r < 4; ++r) {  // combine the 4 col-group waves of this row-group
    float vv = red_m[wr * 4 + 0][g * 4 + r];
    vv = fmaxf(vv, red_m[wr * 4 + 1][g * 4 + r]);
    vv = fmaxf(vv, red_m[wr * 4 + 2][g * 4 + r]);
    vv = fmaxf(vv, red_m[wr * 4 + 3][g * 4 + r]);
    mx[r] = vv;
  }
  float sm[4] = {0.f, 0.f, 0.f, 0.f};
#pragma unroll
  for (int kt = 0; kt < 32; ++kt) {
#pragma unroll
    for (int r = 0; r < 4; ++r) {
      float e = __expf(acc[kt][r] - mx[r]);
      acc[kt][r] = e;
      sm[r] += e;
    }
  }
#pragma unroll
  for (int r = 0; r < 4; ++r) {
    float vv = sm[r];
    vv += __shfl_xor(vv, 1);
    vv += __shfl_xor(vv, 2);
    vv += __shfl_xor(vv, 4);
    vv += __shfl_xor(vv, 8);
    sm[r] = vv;
  }
  if (ln == 0) {
#pragma unroll
    for (int r = 0; r < 4; ++r) red_s[w][g * 4 + r] = sm[r];
  }
  __syncthreads();
  float inv[4];
#pragma unroll
  for (int r = 0; r < 4; ++r) {
    float t = red_s[wr * 4 + 0][g * 4 + r] + red_s[wr * 4 + 1][g * 4 + r] +
              red_s[wr * 4 + 2][g * 4 + r] + red_s[wr * 4 + 3][g * 4 + r];
    inv[r] = 1.0f / t;
  }
#pragma unroll
  for (int kt = 0; kt < 32; ++kt) {
    const int col = kt * 64 + wc * 16 + ln;
#pragma unroll
    for (int r = 0; r < 4; ++r)
      p[(size_t)(row_base + r) * L_ + col] = acc[kt][r] * inv[r];
  }
}

// ---------------- Kernel 2: O = P @ V ----------------
// grid: B*H*(L/128) blocks of 512 threads; wave w owns q-rows [q0+16w, +16).
__global__ __launch_bounds__(512, 4) void pv_kernel(
    const float* __restrict__ Pg, const float* __restrict__ Vg,
    float* __restrict__ Og) {
  const int tid = threadIdx.x;
  const int w = tid >> 6, lane = tid & 63;
  const int g = lane >> 4, ln = lane & 15;

  const int nq = L_ / 128;  // 16
  const int blk = blockIdx.x;
  const int q0 = (blk % nq) * 128;
  const int bh = blk / nq;

  const float* p = Pg + (size_t)bh * L_ * L_;
  const float* v = Vg + (size_t)bh * L_ * D_;
  float* o = Og + (size_t)bh * L_ * D_;

  __shared__ short vt_lds[64 * 64];  // VT[d][k] bf16, swizzled; 8KB

  f32x4 acc[4];
#pragma unroll
  for (int n = 0; n < 4; ++n) acc[n] = f32x4{0.f, 0.f, 0.f, 0.f};

  const float* prp = p + (size_t)(q0 + w * 16 + ln) * L_;
  const int kp = tid & 31;        // k-pair index for staging
  const int d0 = (tid >> 5) * 4;  // 4 d-rows per thread

  for (int kt = 0; kt < 32; ++kt) {
    __syncthreads();
    {
      // stage V tile transposed: VT[d][k], bf16 pairs packed into b32 writes
      const float* vr0 = v + (size_t)(kt * 64 + kp * 2) * D_ + d0;
      float4 f0 = *(const float4*)vr0;
      float4 f1 = *(const float4*)(vr0 + D_);
      unsigned pk[4];
      pk[0] = (unsigned)(unsigned short)f2bf(f0.x) | ((unsigned)(unsigned short)f2bf(f1.x) << 16);
      pk[1] = (unsigned)(unsigned short)f2bf(f0.y) | ((unsigned)(unsigned short)f2bf(f1.y) << 16);
      pk[2] = (unsigned)(unsigned short)f2bf(f0.z) | ((unsigned)(unsigned short)f2bf(f1.z) << 16);
      pk[3] = (unsigned)(unsigned short)f2bf(f0.w) | ((unsigned)(unsigned short)f2bf(f1.w) << 16);
#pragma unroll
      for (int j = 0; j < 4; ++j) {
        int row = d0 + j;
        *(unsigned*)((char*)vt_lds + row * 128 + ((kp * 4) ^ ((row & 7) << 4))) = pk[j];
      }
    }
    __syncthreads();
    // A frags: P rows, f32 -> bf16; slot map k = kt*64 + c*32 + g*8 + e
    bf16x8 pa[2];
#pragma unroll
    for (int c = 0; c < 2; ++c) {
      const float* src = prp + kt * 64 + c * 32 + g * 8;
      float4 f0 = *(const float4*)src;
      float4 f1 = *(const float4*)(src + 4);
      pa[c][0] = f2bf(f0.x); pa[c][1] = f2bf(f0.y);
      pa[c][2] = f2bf(f0.z); pa[c][3] = f2bf(f0.w);
      pa[c][4] = f2bf(f1.x); pa[c][5] = f2bf(f1.y);
      pa[c][6] = f2bf(f1.z); pa[c][7] = f2bf(f1.w);
    }
#pragma unroll
    for (int c = 0; c < 2; ++c) {
#pragma unroll
      for (int n = 0; n < 4; ++n) {
        const int vrow = n * 16 + ln;  // d-column this lane provides
        bf16x8 bf = *(const bf16x8*)((const char*)vt_lds + vrow * 128 +
                                     ((c * 64 + g * 16) ^ ((vrow & 7) << 4)));
        acc[n] = __builtin_amdgcn_mfma_f32_16x16x32_bf16(pa[c], bf, acc[n], 0, 0, 0);
      }
    }
  }
  const int orow = q0 + w * 16 + g * 4;
#pragma unroll
  for (int n = 0; n < 4; ++n)
#pragma unroll
    for (int r = 0; r < 4; ++r)
      o[(size_t)(orow + r) * D_ + n * 16 + ln] = acc[n][r];
}

extern "C" void kernel_launch(void* const* d_in, const int* in_sizes, int n_in,
                              void* d_out, int out_size, void* d_ws, size_t ws_size,
                              hipStream_t stream) {
  const float* q = (const float*)d_in[0];
  const float* k = (const float*)d_in[1];
  const float* v = (const float*)d_in[2];
  const float* mask = (const float*)d_in[3];
  float* out = (float*)d_out;                          // [B,H,L,D]
  float* score = out + (size_t)B_ * H_ * L_ * D_;      // [B,H,L,L]

  qk_softmax_kernel<<<B_ * H_ * (L_ / 32), 512, 0, stream>>>(q, k, mask, score);
  pv_kernel<<<B_ * H_ * (L_ / 128), 512, 0, stream>>>(score, v, out);
}

// Round 2
// 730.743 us; speedup vs baseline: 1.1019x; 1.1019x over previous
//
#include <hip/hip_runtime.h>

typedef __attribute__((ext_vector_type(8))) short bf16x8;
typedef __attribute__((ext_vector_type(4))) float f32x4;
typedef __attribute__((ext_vector_type(4))) short s16x4;

#define DEV static __device__ __forceinline__

constexpr int B_ = 2, H_ = 16, L_ = 2048, D_ = 64;
constexpr float SCALE = 0.125f;  // 1/sqrt(64)

DEV short f2bf(float f) {
  unsigned u = __builtin_bit_cast(unsigned, f);
  u += 0x7fffu + ((u >> 16) & 1u);  // RNE
  return (short)(u >> 16);
}
DEV unsigned pk2(float lo, float hi) {
  return (unsigned)(unsigned short)f2bf(lo) | ((unsigned)(unsigned short)f2bf(hi) << 16);
}
DEV float bflo(unsigned u) { return __builtin_bit_cast(float, u << 16); }
DEV float bfhi(unsigned u) { return __builtin_bit_cast(float, u & 0xffff0000u); }

DEV void stage_tile(short* dst, const float* ksrc, int kt, int tid) {
  // tile row r <-> global k-row (r>>4)*512 + kt*16 + (r&15); 64 rows x 64 d, bf16, XOR-swizzled
#pragma unroll
  for (int it = 0; it < 4; ++it) {
    int idx = it * 256 + tid;
    int r = idx >> 4, c4 = idx & 15;
    int gk = (r >> 4) * 512 + kt * 16 + (r & 15);
    float4 vv = *(const float4*)(ksrc + (size_t)gk * D_ + c4 * 4);
    s16x4 s;
    s[0] = f2bf(vv.x); s[1] = f2bf(vv.y); s[2] = f2bf(vv.z); s[3] = f2bf(vv.w);
    *(s16x4*)((char*)dst + r * 128 + ((c4 * 8) ^ ((r & 7) << 4))) = s;
  }
}

// ---------------- Kernel 1: P = softmax(QK^T * scale * mask) ----------------
// 256 threads = 4 waves; q-tile 16 rows; wave w owns cols w*512 + kt*16 + ln, kt=0..31.
// Logits stored as packed bf16 pairs in 64 VGPRs -> 4 blocks/CU resident.
__global__ __launch_bounds__(256, 4) void qk_softmax_kernel(
    const float* __restrict__ Qg, const float* __restrict__ Kg,
    const float* __restrict__ Mg, float* __restrict__ Pg) {
  const int tid = threadIdx.x;
  const int w = tid >> 6, lane = tid & 63;
  const int g = lane >> 4, ln = lane & 15;

  const int nq = L_ / 16;  // 128 q-tiles
  const int blk = blockIdx.x;
  const int q0 = (blk % nq) * 16;
  const int bh = blk / nq;
  const int b = bh >> 4;  // H_=16

  const float* q = Qg + (size_t)bh * L_ * D_;
  const float* k = Kg + (size_t)bh * L_ * D_;
  const float* m = Mg + (size_t)b * L_ * L_;
  float* p = Pg + (size_t)bh * L_ * L_;

  __shared__ short kt_lds[2][64 * 64];  // 2 x 8KB bf16, double buffer
  __shared__ float red[4][16];

  // A frag: q-rows q0+ln, slot d = half*32 + g*8 + e (same map as B frags)
  bf16x8 a0, a1;
  {
    const float* qr = q + (size_t)(q0 + ln) * D_ + g * 8;
    float4 f0 = *(const float4*)(qr);
    float4 f1 = *(const float4*)(qr + 4);
    float4 f2 = *(const float4*)(qr + 32);
    float4 f3 = *(const float4*)(qr + 36);
    a0[0] = f2bf(f0.x); a0[1] = f2bf(f0.y); a0[2] = f2bf(f0.z); a0[3] = f2bf(f0.w);
    a0[4] = f2bf(f1.x); a0[5] = f2bf(f1.y); a0[6] = f2bf(f1.z); a0[7] = f2bf(f1.w);
    a1[0] = f2bf(f2.x); a1[1] = f2bf(f2.y); a1[2] = f2bf(f2.z); a1[3] = f2bf(f2.w);
    a1[4] = f2bf(f3.x); a1[5] = f2bf(f3.y); a1[6] = f2bf(f3.z); a1[7] = f2bf(f3.w);
  }

  const int br = (w << 4) + ln;  // K-tile row for this lane's B frag
  const int bswz = (br & 7) << 4;
  const int row_base = q0 + g * 4;
  const int colb = (w << 9) + ln;
  const float* mp = m + (size_t)row_base * L_ + colb;

  unsigned pkv[64];  // packed bf16 logits (then packed bf16 exp)
  float mx0 = -1e30f, mx1 = -1e30f, mx2 = -1e30f, mx3 = -1e30f;

  stage_tile(kt_lds[0], k, 0, tid);
  __syncthreads();

#pragma unroll
  for (int kt = 0; kt < 32; ++kt) {
    const int cur = kt & 1;
    const char* lb = (const char*)kt_lds[cur];
    bf16x8 b0 = *(const bf16x8*)(lb + br * 128 + ((g * 16) ^ bswz));
    bf16x8 b1 = *(const bf16x8*)(lb + br * 128 + ((64 + g * 16) ^ bswz));
    f32x4 acc{0.f, 0.f, 0.f, 0.f};
    acc = __builtin_amdgcn_mfma_f32_16x16x32_bf16(a0, b0, acc, 0, 0, 0);
    acc = __builtin_amdgcn_mfma_f32_16x16x32_bf16(a1, b1, acc, 0, 0, 0);
    float m0 = mp[kt * 16];
    float m1 = mp[L_ + kt * 16];
    float m2 = mp[2 * L_ + kt * 16];
    float m3 = mp[3 * L_ + kt * 16];
    if (kt < 31) stage_tile(kt_lds[cur ^ 1], k, kt + 1, tid);
    float l0 = acc[0] * SCALE * m0;
    float l1 = acc[1] * SCALE * m1;
    float l2 = acc[2] * SCALE * m2;
    float l3 = acc[3] * SCALE * m3;
    mx0 = fmaxf(mx0, l0); mx1 = fmaxf(mx1, l1);
    mx2 = fmaxf(mx2, l2); mx3 = fmaxf(mx3, l3);
    pkv[kt * 2] = pk2(l0, l1);
    pkv[kt * 2 + 1] = pk2(l2, l3);
    __syncthreads();
  }

  // ---- max reduce: 16 lanes (cols) then 4 waves ----
#define LRED_MAX(v) v = fmaxf(v, __shfl_xor(v, 1)); v = fmaxf(v, __shfl_xor(v, 2)); \
                    v = fmaxf(v, __shfl_xor(v, 4)); v = fmaxf(v, __shfl_xor(v, 8));
  LRED_MAX(mx0) LRED_MAX(mx1) LRED_MAX(mx2) LRED_MAX(mx3)
  if (ln == 0) {
    red[w][g * 4 + 0] = mx0; red[w][g * 4 + 1] = mx1;
    red[w][g * 4 + 2] = mx2; red[w][g * 4 + 3] = mx3;
  }
  __syncthreads();
  mx0 = fmaxf(fmaxf(red[0][g * 4 + 0], red[1][g * 4 + 0]), fmaxf(red[2][g * 4 + 0], red[3][g * 4 + 0]));
  mx1 = fmaxf(fmaxf(red[0][g * 4 + 1], red[1][g * 4 + 1]), fmaxf(red[2][g * 4 + 1], red[3][g * 4 + 1]));
  mx2 = fmaxf(fmaxf(red[0][g * 4 + 2], red[1][g * 4 + 2]), fmaxf(red[2][g * 4 + 2], red[3][g * 4 + 2]));
  mx3 = fmaxf(fmaxf(red[0][g * 4 + 3], red[1][g * 4 + 3]), fmaxf(red[2][g * 4 + 3], red[3][g * 4 + 3]));

  // ---- exp + sum (f32 sums), repack e as bf16 ----
  float s0 = 0.f, s1 = 0.f, s2 = 0.f, s3 = 0.f;
#pragma unroll
  for (int kt = 0; kt < 32; ++kt) {
    unsigned u0 = pkv[kt * 2], u1 = pkv[kt * 2 + 1];
    float e0 = __expf(bflo(u0) - mx0);
    float e1 = __expf(bfhi(u0) - mx1);
    float e2 = __expf(bflo(u1) - mx2);
    float e3 = __expf(bfhi(u1) - mx3);
    s0 += e0; s1 += e1; s2 += e2; s3 += e3;
    pkv[kt * 2] = pk2(e0, e1);
    pkv[kt * 2 + 1] = pk2(e2, e3);
  }
#define LRED_SUM(v) v += __shfl_xor(v, 1); v += __shfl_xor(v, 2); \
                    v += __shfl_xor(v, 4); v += __shfl_xor(v, 8);
  LRED_SUM(s0) LRED_SUM(s1) LRED_SUM(s2) LRED_SUM(s3)
  __syncthreads();  // everyone done reading red (max phase)
  if (ln == 0) {
    red[w][g * 4 + 0] = s0; red[w][g * 4 + 1] = s1;
    red[w][g * 4 + 2] = s2; red[w][g * 4 + 3] = s3;
  }
  __syncthreads();
  float inv0 = 1.0f / (red[0][g * 4 + 0] + red[1][g * 4 + 0] + red[2][g * 4 + 0] + red[3][g * 4 + 0]);
  float inv1 = 1.0f / (red[0][g * 4 + 1] + red[1][g * 4 + 1] + red[2][g * 4 + 1] + red[3][g * 4 + 1]);
  float inv2 = 1.0f / (red[0][g * 4 + 2] + red[1][g * 4 + 2] + red[2][g * 4 + 2] + red[3][g * 4 + 2]);
  float inv3 = 1.0f / (red[0][g * 4 + 3] + red[1][g * 4 + 3] + red[2][g * 4 + 3] + red[3][g * 4 + 3]);

  // ---- write P ----
  float* pp = p + (size_t)row_base * L_ + colb;
#pragma unroll
  for (int kt = 0; kt < 32; ++kt) {
    unsigned u0 = pkv[kt * 2], u1 = pkv[kt * 2 + 1];
    pp[kt * 16] = bflo(u0) * inv0;
    pp[L_ + kt * 16] = bfhi(u0) * inv1;
    pp[2 * L_ + kt * 16] = bflo(u1) * inv2;
    pp[3 * L_ + kt * 16] = bfhi(u1) * inv3;
  }
}

// ---------------- Kernel 2: O = P @ V ----------------
__global__ __launch_bounds__(512, 4) void pv_kernel(
    const float* __restrict__ Pg, const float* __restrict__ Vg,
    float* __restrict__ Og) {
  const int tid = threadIdx.x;
  const int w = tid >> 6, lane = tid & 63;
  const int g = lane >> 4, ln = lane & 15;

  const int nq = L_ / 128;  // 16
  const int blk = blockIdx.x;
  const int q0 = (blk % nq) * 128;
  const int bh = blk / nq;

  const float* p = Pg + (size_t)bh * L_ * L_;
  const float* v = Vg + (size_t)bh * L_ * D_;
  float* o = Og + (size_t)bh * L_ * D_;

  __shared__ short vt_lds[64 * 64];  // VT[d][k] bf16, swizzled

  f32x4 acc[4];
#pragma unroll
  for (int n = 0; n < 4; ++n) acc[n] = f32x4{0.f, 0.f, 0.f, 0.f};

  const float* prp = p + (size_t)(q0 + w * 16 + ln) * L_;
  const int kp = tid & 31;
  const int d0 = (tid >> 5) * 4;

  for (int kt = 0; kt < 32; ++kt) {
    __syncthreads();
    {
      const float* vr0 = v + (size_t)(kt * 64 + kp * 2) * D_ + d0;
      float4 f0 = *(const float4*)vr0;
      float4 f1 = *(const float4*)(vr0 + D_);
      unsigned pkx[4];
      pkx[0] = pk2(f0.x, f1.x);
      pkx[1] = pk2(f0.y, f1.y);
      pkx[2] = pk2(f0.z, f1.z);
      pkx[3] = pk2(f0.w, f1.w);
#pragma unroll
      for (int j = 0; j < 4; ++j) {
        int row = d0 + j;
        *(unsigned*)((char*)vt_lds + row * 128 + ((kp * 4) ^ ((row & 7) << 4))) = pkx[j];
      }
    }
    __syncthreads();
    bf16x8 pa[2];
#pragma unroll
    for (int c = 0; c < 2; ++c) {
      const float* src = prp + kt * 64 + c * 32 + g * 8;
      float4 f0 = *(const float4*)src;
      float4 f1 = *(const float4*)(src + 4);
      pa[c][0] = f2bf(f0.x); pa[c][1] = f2bf(f0.y);
      pa[c][2] = f2bf(f0.z); pa[c][3] = f2bf(f0.w);
      pa[c][4] = f2bf(f1.x); pa[c][5] = f2bf(f1.y);
      pa[c][6] = f2bf(f1.z); pa[c][7] = f2bf(f1.w);
    }
#pragma unroll
    for (int c = 0; c < 2; ++c) {
#pragma unroll
      for (int n = 0; n < 4; ++n) {
        const int vrow = n * 16 + ln;
        bf16x8 bf = *(const bf16x8*)((const char*)vt_lds + vrow * 128 +
                                     ((c * 64 + g * 16) ^ ((vrow & 7) << 4)));
        acc[n] = __builtin_amdgcn_mfma_f32_16x16x32_bf16(pa[c], bf, acc[n], 0, 0, 0);
      }
    }
  }
  const int orow = q0 + w * 16 + g * 4;
#pragma unroll
  for (int n = 0; n < 4; ++n)
#pragma unroll
    for (int r = 0; r < 4; ++r)
      o[(size_t)(orow + r) * D_ + n * 16 + ln] = acc[n][r];
}

extern "C" void kernel_launch(void* const* d_in, const int* in_sizes, int n_in,
                              void* d_out, int out_size, void* d_ws, size_t ws_size,
                              hipStream_t stream) {
  const float* q = (const float*)d_in[0];
  const float* k = (const float*)d_in[1];
  const float* v = (const float*)d_in[2];
  const float* mask = (const float*)d_in[3];
  float* out = (float*)d_out;                      // [B,H,L,D]
  float* score = out + (size_t)B_ * H_ * L_ * D_;  // [B,H,L,L]

  qk_softmax_kernel<<<B_ * H_ * (L_ / 16), 256, 0, stream>>>(q, k, mask, score);
  pv_kernel<<<B_ * H_ * (L_ / 128), 512, 0, stream>>>(score, v, out);
}

// Round 3
// 624.758 us; speedup vs baseline: 1.2888x; 1.1696x over previous
//
#include <hip/hip_runtime.h>

typedef __attribute__((ext_vector_type(8))) short bf16x8;
typedef __attribute__((ext_vector_type(4))) float f32x4;

#define DEV static __device__ __forceinline__

constexpr int B_ = 2, H_ = 16, L_ = 2048, D_ = 64;
constexpr float SCALE = 0.125f;  // 1/sqrt(64)

DEV short f2bf(float f) {
  unsigned u = __builtin_bit_cast(unsigned, f);
  u += 0x7fffu + ((u >> 16) & 1u);  // RNE
  return (short)(u >> 16);
}
DEV unsigned pk2(float lo, float hi) {
  return (unsigned)(unsigned short)f2bf(lo) | ((unsigned)(unsigned short)f2bf(hi) << 16);
}
DEV float bflo(unsigned u) { return __builtin_bit_cast(float, u << 16); }
DEV float bfhi(unsigned u) { return __builtin_bit_cast(float, u & 0xffff0000u); }

DEV bf16x8 frag_from(const float* src) {  // 8 consecutive f32 -> bf16x8
  float4 f0 = *(const float4*)src;
  float4 f1 = *(const float4*)(src + 4);
  bf16x8 r;
  r[0] = f2bf(f0.x); r[1] = f2bf(f0.y); r[2] = f2bf(f0.z); r[3] = f2bf(f0.w);
  r[4] = f2bf(f1.x); r[5] = f2bf(f1.y); r[6] = f2bf(f1.z); r[7] = f2bf(f1.w);
  return r;
}

// ---------------- Kernel 1: P = softmax(QK^T * scale * mask) ----------------
// 256 threads = 4 waves; q-tile 16 rows; wave w owns cols w*512 + kt*16 + ln.
// NO LDS staging: B-frags load straight from global K (8 consecutive d per lane).
// No barriers in the k-loop -> compiler software-pipelines the 8 loads/iter.
__global__ __launch_bounds__(256, 4) void qk_softmax_kernel(
    const float* __restrict__ Qg, const float* __restrict__ Kg,
    const float* __restrict__ Mg, float* __restrict__ Pg) {
  const int tid = threadIdx.x;
  const int w = tid >> 6, lane = tid & 63;
  const int g = lane >> 4, ln = lane & 15;

  const int nq = L_ / 16;  // 128 q-tiles
  const int blk = blockIdx.x;
  const int q0 = (blk % nq) * 16;
  const int bh = blk / nq;
  const int b = bh >> 4;  // H_=16

  const float* q = Qg + (size_t)bh * L_ * D_;
  const float* k = Kg + (size_t)bh * L_ * D_;
  const float* m = Mg + (size_t)b * L_ * L_;
  float* p = Pg + (size_t)bh * L_ * L_;

  __shared__ float red[4][16];

  // A frag: q-row q0+ln, slot d = half*32 + g*8 + e (B frags use the same map)
  bf16x8 a0 = frag_from(q + (size_t)(q0 + ln) * D_ + g * 8);
  bf16x8 a1 = frag_from(q + (size_t)(q0 + ln) * D_ + 32 + g * 8);

  const int colb = (w << 9) + ln;     // this lane's k-column (= K row) base
  const int row_base = q0 + g * 4;
  const float* kb = k + (size_t)colb * D_;
  const float* mp = m + (size_t)row_base * L_ + colb;

  unsigned pkv[64];  // packed bf16 logits (then packed bf16 exp)
  float mx0 = -1e30f, mx1 = -1e30f, mx2 = -1e30f, mx3 = -1e30f;

#pragma unroll
  for (int kt = 0; kt < 32; ++kt) {
    const float* kr = kb + kt * 16 * D_;   // K row colb + kt*16
    bf16x8 b0 = frag_from(kr + g * 8);
    bf16x8 b1 = frag_from(kr + 32 + g * 8);
    f32x4 acc{0.f, 0.f, 0.f, 0.f};
    acc = __builtin_amdgcn_mfma_f32_16x16x32_bf16(a0, b0, acc, 0, 0, 0);
    acc = __builtin_amdgcn_mfma_f32_16x16x32_bf16(a1, b1, acc, 0, 0, 0);
    float m0 = mp[kt * 16];
    float m1 = mp[L_ + kt * 16];
    float m2 = mp[2 * L_ + kt * 16];
    float m3 = mp[3 * L_ + kt * 16];
    float l0 = acc[0] * SCALE * m0;
    float l1 = acc[1] * SCALE * m1;
    float l2 = acc[2] * SCALE * m2;
    float l3 = acc[3] * SCALE * m3;
    mx0 = fmaxf(mx0, l0); mx1 = fmaxf(mx1, l1);
    mx2 = fmaxf(mx2, l2); mx3 = fmaxf(mx3, l3);
    pkv[kt * 2] = pk2(l0, l1);
    pkv[kt * 2 + 1] = pk2(l2, l3);
  }

  // ---- max reduce: 16 lanes (cols) then 4 waves ----
#define LRED_MAX(v) v = fmaxf(v, __shfl_xor(v, 1)); v = fmaxf(v, __shfl_xor(v, 2)); \
                    v = fmaxf(v, __shfl_xor(v, 4)); v = fmaxf(v, __shfl_xor(v, 8));
  LRED_MAX(mx0) LRED_MAX(mx1) LRED_MAX(mx2) LRED_MAX(mx3)
  if (ln == 0) {
    red[w][g * 4 + 0] = mx0; red[w][g * 4 + 1] = mx1;
    red[w][g * 4 + 2] = mx2; red[w][g * 4 + 3] = mx3;
  }
  __syncthreads();
  mx0 = fmaxf(fmaxf(red[0][g * 4 + 0], red[1][g * 4 + 0]), fmaxf(red[2][g * 4 + 0], red[3][g * 4 + 0]));
  mx1 = fmaxf(fmaxf(red[0][g * 4 + 1], red[1][g * 4 + 1]), fmaxf(red[2][g * 4 + 1], red[3][g * 4 + 1]));
  mx2 = fmaxf(fmaxf(red[0][g * 4 + 2], red[1][g * 4 + 2]), fmaxf(red[2][g * 4 + 2], red[3][g * 4 + 2]));
  mx3 = fmaxf(fmaxf(red[0][g * 4 + 3], red[1][g * 4 + 3]), fmaxf(red[2][g * 4 + 3], red[3][g * 4 + 3]));

  // ---- exp + sum (f32 sums), repack e as bf16 ----
  float s0 = 0.f, s1 = 0.f, s2 = 0.f, s3 = 0.f;
#pragma unroll
  for (int kt = 0; kt < 32; ++kt) {
    unsigned u0 = pkv[kt * 2], u1 = pkv[kt * 2 + 1];
    float e0 = __expf(bflo(u0) - mx0);
    float e1 = __expf(bfhi(u0) - mx1);
    float e2 = __expf(bflo(u1) - mx2);
    float e3 = __expf(bfhi(u1) - mx3);
    s0 += e0; s1 += e1; s2 += e2; s3 += e3;
    pkv[kt * 2] = pk2(e0, e1);
    pkv[kt * 2 + 1] = pk2(e2, e3);
  }
#define LRED_SUM(v) v += __shfl_xor(v, 1); v += __shfl_xor(v, 2); \
                    v += __shfl_xor(v, 4); v += __shfl_xor(v, 8);
  LRED_SUM(s0) LRED_SUM(s1) LRED_SUM(s2) LRED_SUM(s3)
  __syncthreads();  // everyone done reading red (max phase)
  if (ln == 0) {
    red[w][g * 4 + 0] = s0; red[w][g * 4 + 1] = s1;
    red[w][g * 4 + 2] = s2; red[w][g * 4 + 3] = s3;
  }
  __syncthreads();
  float inv0 = 1.0f / (red[0][g * 4 + 0] + red[1][g * 4 + 0] + red[2][g * 4 + 0] + red[3][g * 4 + 0]);
  float inv1 = 1.0f / (red[0][g * 4 + 1] + red[1][g * 4 + 1] + red[2][g * 4 + 1] + red[3][g * 4 + 1]);
  float inv2 = 1.0f / (red[0][g * 4 + 2] + red[1][g * 4 + 2] + red[2][g * 4 + 2] + red[3][g * 4 + 2]);
  float inv3 = 1.0f / (red[0][g * 4 + 3] + red[1][g * 4 + 3] + red[2][g * 4 + 3] + red[3][g * 4 + 3]);

  // ---- write P (nontemporal: don't churn L2/L3 -- keep the mask resident) ----
  float* pp = p + (size_t)row_base * L_ + colb;
#pragma unroll
  for (int kt = 0; kt < 32; ++kt) {
    unsigned u0 = pkv[kt * 2], u1 = pkv[kt * 2 + 1];
    __builtin_nontemporal_store(bflo(u0) * inv0, pp + kt * 16);
    __builtin_nontemporal_store(bfhi(u0) * inv1, pp + L_ + kt * 16);
    __builtin_nontemporal_store(bflo(u1) * inv2, pp + 2 * L_ + kt * 16);
    __builtin_nontemporal_store(bfhi(u1) * inv3, pp + 3 * L_ + kt * 16);
  }
}

// ---------------- Kernel 2: O = P @ V ----------------
// 512 threads, q-tile 128 rows; V double-buffered in LDS (1 barrier/iter);
// P A-frags register-prefetched one iteration ahead.
__global__ __launch_bounds__(512, 2) void pv_kernel(
    const float* __restrict__ Pg, const float* __restrict__ Vg,
    float* __restrict__ Og) {
  const int tid = threadIdx.x;
  const int w = tid >> 6, lane = tid & 63;
  const int g = lane >> 4, ln = lane & 15;

  const int nq = L_ / 128;  // 16
  const int blk = blockIdx.x;
  const int q0 = (blk % nq) * 128;
  const int bh = blk / nq;

  const float* p = Pg + (size_t)bh * L_ * L_;
  const float* v = Vg + (size_t)bh * L_ * D_;
  float* o = Og + (size_t)bh * L_ * D_;

  __shared__ short vt_lds[2][64 * 64];  // VT[d][k] bf16 (packed pairs), swizzled

  f32x4 acc[4];
#pragma unroll
  for (int n = 0; n < 4; ++n) acc[n] = f32x4{0.f, 0.f, 0.f, 0.f};

  const float* prp = p + (size_t)(q0 + w * 16 + ln) * L_;
  const int kp = tid & 31;
  const int d0 = (tid >> 5) * 4;

  // stage V tile kt (64 k-rows x 64 d) transposed into buf
#define STAGE_V(buf, kt)                                                        \
  {                                                                             \
    const float* vr0 = v + (size_t)((kt) * 64 + kp * 2) * D_ + d0;              \
    float4 f0 = *(const float4*)vr0;                                            \
    float4 f1 = *(const float4*)(vr0 + D_);                                     \
    unsigned pkx0 = pk2(f0.x, f1.x), pkx1 = pk2(f0.y, f1.y);                    \
    unsigned pkx2 = pk2(f0.z, f1.z), pkx3 = pk2(f0.w, f1.w);                    \
    *(unsigned*)((char*)vt_lds[buf] + (d0 + 0) * 128 + ((kp * 4) ^ (((d0 + 0) & 7) << 4))) = pkx0; \
    *(unsigned*)((char*)vt_lds[buf] + (d0 + 1) * 128 + ((kp * 4) ^ (((d0 + 1) & 7) << 4))) = pkx1; \
    *(unsigned*)((char*)vt_lds[buf] + (d0 + 2) * 128 + ((kp * 4) ^ (((d0 + 2) & 7) << 4))) = pkx2; \
    *(unsigned*)((char*)vt_lds[buf] + (d0 + 3) * 128 + ((kp * 4) ^ (((d0 + 3) & 7) << 4))) = pkx3; \
  }

  // P prefetch registers (raw f32, converted at use)
  float4 pf0, pf1, pf2, pf3;
#define LOAD_P(kt)                                                \
  {                                                               \
    const float* src = prp + (kt) * 64;                           \
    pf0 = *(const float4*)(src + g * 8);                          \
    pf1 = *(const float4*)(src + g * 8 + 4);                      \
    pf2 = *(const float4*)(src + 32 + g * 8);                     \
    pf3 = *(const float4*)(src + 32 + g * 8 + 4);                 \
  }

  STAGE_V(0, 0)
  LOAD_P(0)
  __syncthreads();

  for (int kt = 0; kt < 32; ++kt) {
    const int cur = kt & 1;
    // convert current P frags out of the prefetch regs
    bf16x8 pa0, pa1;
    pa0[0] = f2bf(pf0.x); pa0[1] = f2bf(pf0.y); pa0[2] = f2bf(pf0.z); pa0[3] = f2bf(pf0.w);
    pa0[4] = f2bf(pf1.x); pa0[5] = f2bf(pf1.y); pa0[6] = f2bf(pf1.z); pa0[7] = f2bf(pf1.w);
    pa1[0] = f2bf(pf2.x); pa1[1] = f2bf(pf2.y); pa1[2] = f2bf(pf2.z); pa1[3] = f2bf(pf2.w);
    pa1[4] = f2bf(pf3.x); pa1[5] = f2bf(pf3.y); pa1[6] = f2bf(pf3.z); pa1[7] = f2bf(pf3.w);
    if (kt < 31) {
      STAGE_V(cur ^ 1, kt + 1)
      LOAD_P(kt + 1)
    }
#pragma unroll
    for (int n = 0; n < 4; ++n) {
      const int vrow = n * 16 + ln;
      const int swz = (vrow & 7) << 4;
      bf16x8 bf0 = *(const bf16x8*)((const char*)vt_lds[cur] + vrow * 128 + ((g * 16) ^ swz));
      bf16x8 bf1 = *(const bf16x8*)((const char*)vt_lds[cur] + vrow * 128 + ((64 + g * 16) ^ swz));
      acc[n] = __builtin_amdgcn_mfma_f32_16x16x32_bf16(pa0, bf0, acc[n], 0, 0, 0);
      acc[n] = __builtin_amdgcn_mfma_f32_16x16x32_bf16(pa1, bf1, acc[n], 0, 0, 0);
    }
    __syncthreads();
  }
  const int orow = q0 + w * 16 + g * 4;
#pragma unroll
  for (int n = 0; n < 4; ++n)
#pragma unroll
    for (int r = 0; r < 4; ++r)
      __builtin_nontemporal_store(acc[n][r], o + (size_t)(orow + r) * D_ + n * 16 + ln);
}

extern "C" void kernel_launch(void* const* d_in, const int* in_sizes, int n_in,
                              void* d_out, int out_size, void* d_ws, size_t ws_size,
                              hipStream_t stream) {
  const float* q = (const float*)d_in[0];
  const float* k = (const float*)d_in[1];
  const float* v = (const float*)d_in[2];
  const float* mask = (const float*)d_in[3];
  float* out = (float*)d_out;                      // [B,H,L,D]
  float* score = out + (size_t)B_ * H_ * L_ * D_;  // [B,H,L,L]

  qk_softmax_kernel<<<B_ * H_ * (L_ / 16), 256, 0, stream>>>(q, k, mask, score);
  pv_kernel<<<B_ * H_ * (L_ / 128), 512, 0, stream>>>(score, v, out);
}

// Round 5
// 330.293 us; speedup vs baseline: 2.4379x; 1.8915x over previous
//
#include <hip/hip_runtime.h>

typedef __attribute__((ext_vector_type(8))) short bf16x8;
typedef __attribute__((ext_vector_type(4))) float f32x4;

#define DEV static __device__ __forceinline__

constexpr int B_ = 2, H_ = 16, L_ = 2048, D_ = 64;
constexpr float SCALE = 0.125f;  // 1/sqrt(64)

DEV short f2bf(float f) {
  unsigned u = __builtin_bit_cast(unsigned, f);
  u += 0x7fffu + ((u >> 16) & 1u);  // RNE
  return (short)(u >> 16);
}
DEV unsigned pk2(float lo, float hi) {
  return (unsigned)(unsigned short)f2bf(lo) | ((unsigned)(unsigned short)f2bf(hi) << 16);
}
DEV float bflo(unsigned u) { return __builtin_bit_cast(float, u << 16); }
DEV float bfhi(unsigned u) { return __builtin_bit_cast(float, u & 0xffff0000u); }

DEV bf16x8 frag_from(const float* src) {  // 8 consecutive f32 -> bf16x8
  float4 f0 = *(const float4*)src;
  float4 f1 = *(const float4*)(src + 4);
  bf16x8 r;
  r[0] = f2bf(f0.x); r[1] = f2bf(f0.y); r[2] = f2bf(f0.z); r[3] = f2bf(f0.w);
  r[4] = f2bf(f1.x); r[5] = f2bf(f1.y); r[6] = f2bf(f1.z); r[7] = f2bf(f1.w);
  return r;
}

// ---------------- Pre-pass: K (f32) -> fragment-linear bf16 in ws ----------------
// Kp layout (bf16x8 units): [bh][ktile 0..127][half 0..1][lane 0..63]
// where lane=g*16+ln holds K[bh][ktile*16+ln][half*32+g*8 .. +8).
__global__ __launch_bounds__(256) void convert_k_kernel(
    const float* __restrict__ Kg, short* __restrict__ Kp) {
  const int tid = threadIdx.x;
  const int lane = tid & 63, half = (tid >> 6) & 1, sub = tid >> 7;
  const int blk = blockIdx.x;               // 2048 blocks
  const int bh = blk >> 6;                  // 32
  const int ktile = (((blk & 63) << 1) | sub);  // 0..127
  const int g = lane >> 4, ln = lane & 15;
  const float* src = Kg + ((size_t)bh * L_ + ktile * 16 + ln) * D_ + half * 32 + g * 8;
  bf16x8 f = frag_from(src);
  *(bf16x8*)(Kp + ((((size_t)(bh * 128 + ktile)) * 2 + half) * 64 + lane) * 8) = f;
}

// ---------------- Kernel 1: P = softmax(QK^T * scale * mask) ----------------
// 512 threads = 8 waves; q-tile 16 rows; wave w owns cols w*256 + kt*16 + ln, kt=0..15.
// pkv[32] packed bf16 logits/exps -> fits registers (no spill).
template <bool USEKP>
__global__ __launch_bounds__(512, 2) void qk_softmax_kernel(
    const float* __restrict__ Qg, const float* __restrict__ Kg,
    const short* __restrict__ Kp, const float* __restrict__ Mg,
    float* __restrict__ Pg) {
  const int tid = threadIdx.x;
  const int w = tid >> 6, lane = tid & 63;
  const int g = lane >> 4, ln = lane & 15;

  const int nq = L_ / 16;  // 128 q-tiles
  const int blk = blockIdx.x;
  const int q0 = (blk % nq) * 16;
  const int bh = blk / nq;
  const int b = bh >> 4;  // H_=16

  const float* q = Qg + (size_t)bh * L_ * D_;
  const float* k = Kg + (size_t)bh * L_ * D_;
  const float* m = Mg + (size_t)b * L_ * L_;
  float* p = Pg + (size_t)bh * L_ * L_;

  __shared__ float red[8][16];

  // A frag: q-row q0+ln, slot d = half*32 + g*8 + e (B frags use the same map)
  bf16x8 a0 = frag_from(q + (size_t)(q0 + ln) * D_ + g * 8);
  bf16x8 a1 = frag_from(q + (size_t)(q0 + ln) * D_ + 32 + g * 8);

  const int colb = (w << 8) + ln;  // this lane's k-column base
  const int row_base = q0 + g * 4;
  const float* mp = m + (size_t)row_base * L_ + colb;
  // fragment-linear K pointer: tiles w*16 + kt, strides: kt -> 128 frags, half -> 64
  const bf16x8* kpb = (const bf16x8*)Kp + ((size_t)bh * 128 + w * 16) * 2 * 64 + lane;

  unsigned pkv[32];  // packed bf16 logits (then packed bf16 exp)
  float mx0 = -1e30f, mx1 = -1e30f, mx2 = -1e30f, mx3 = -1e30f;

#pragma unroll
  for (int kt = 0; kt < 16; ++kt) {
    bf16x8 b0, b1;
    if (USEKP) {
      b0 = kpb[kt * 128];
      b1 = kpb[kt * 128 + 64];
    } else {
      const float* kr = k + (size_t)((w << 8) + kt * 16 + ln) * D_;
      b0 = frag_from(kr + g * 8);
      b1 = frag_from(kr + 32 + g * 8);
    }
    f32x4 acc{0.f, 0.f, 0.f, 0.f};
    acc = __builtin_amdgcn_mfma_f32_16x16x32_bf16(a0, b0, acc, 0, 0, 0);
    acc = __builtin_amdgcn_mfma_f32_16x16x32_bf16(a1, b1, acc, 0, 0, 0);
    float m0 = mp[kt * 16];
    float m1 = mp[L_ + kt * 16];
    float m2 = mp[2 * L_ + kt * 16];
    float m3 = mp[3 * L_ + kt * 16];
    float l0 = acc[0] * SCALE * m0;
    float l1 = acc[1] * SCALE * m1;
    float l2 = acc[2] * SCALE * m2;
    float l3 = acc[3] * SCALE * m3;
    mx0 = fmaxf(mx0, l0); mx1 = fmaxf(mx1, l1);
    mx2 = fmaxf(mx2, l2); mx3 = fmaxf(mx3, l3);
    pkv[kt * 2] = pk2(l0, l1);
    pkv[kt * 2 + 1] = pk2(l2, l3);
  }

  // ---- max reduce: 16 lanes (cols) then 8 waves ----
#define LRED_MAX(v) v = fmaxf(v, __shfl_xor(v, 1)); v = fmaxf(v, __shfl_xor(v, 2)); \
                    v = fmaxf(v, __shfl_xor(v, 4)); v = fmaxf(v, __shfl_xor(v, 8));
  LRED_MAX(mx0) LRED_MAX(mx1) LRED_MAX(mx2) LRED_MAX(mx3)
  if (ln == 0) {
    red[w][g * 4 + 0] = mx0; red[w][g * 4 + 1] = mx1;
    red[w][g * 4 + 2] = mx2; red[w][g * 4 + 3] = mx3;
  }
  __syncthreads();
  {
    float t0 = red[0][g * 4 + 0], t1 = red[0][g * 4 + 1], t2 = red[0][g * 4 + 2], t3 = red[0][g * 4 + 3];
#pragma unroll
    for (int ww = 1; ww < 8; ++ww) {
      t0 = fmaxf(t0, red[ww][g * 4 + 0]);
      t1 = fmaxf(t1, red[ww][g * 4 + 1]);
      t2 = fmaxf(t2, red[ww][g * 4 + 2]);
      t3 = fmaxf(t3, red[ww][g * 4 + 3]);
    }
    mx0 = t0; mx1 = t1; mx2 = t2; mx3 = t3;
  }

  // ---- exp + sum (f32 sums), repack e as bf16 ----
  float s0 = 0.f, s1 = 0.f, s2 = 0.f, s3 = 0.f;
#pragma unroll
  for (int kt = 0; kt < 16; ++kt) {
    unsigned u0 = pkv[kt * 2], u1 = pkv[kt * 2 + 1];
    float e0 = __expf(bflo(u0) - mx0);
    float e1 = __expf(bfhi(u0) - mx1);
    float e2 = __expf(bflo(u1) - mx2);
    float e3 = __expf(bfhi(u1) - mx3);
    s0 += e0; s1 += e1; s2 += e2; s3 += e3;
    pkv[kt * 2] = pk2(e0, e1);
    pkv[kt * 2 + 1] = pk2(e2, e3);
  }
#define LRED_SUM(v) v += __shfl_xor(v, 1); v += __shfl_xor(v, 2); \
                    v += __shfl_xor(v, 4); v += __shfl_xor(v, 8);
  LRED_SUM(s0) LRED_SUM(s1) LRED_SUM(s2) LRED_SUM(s3)
  __syncthreads();  // everyone done reading red (max phase)
  if (ln == 0) {
    red[w][g * 4 + 0] = s0; red[w][g * 4 + 1] = s1;
    red[w][g * 4 + 2] = s2; red[w][g * 4 + 3] = s3;
  }
  __syncthreads();
  float inv0, inv1, inv2, inv3;
  {
    float t0 = red[0][g * 4 + 0], t1 = red[0][g * 4 + 1], t2 = red[0][g * 4 + 2], t3 = red[0][g * 4 + 3];
#pragma unroll
    for (int ww = 1; ww < 8; ++ww) {
      t0 += red[ww][g * 4 + 0];
      t1 += red[ww][g * 4 + 1];
      t2 += red[ww][g * 4 + 2];
      t3 += red[ww][g * 4 + 3];
    }
    inv0 = 1.0f / t0; inv1 = 1.0f / t1; inv2 = 1.0f / t2; inv3 = 1.0f / t3;
  }

  // ---- write P (nontemporal: don't churn L2/L3) ----
  float* pp = p + (size_t)row_base * L_ + colb;
#pragma unroll
  for (int kt = 0; kt < 16; ++kt) {
    unsigned u0 = pkv[kt * 2], u1 = pkv[kt * 2 + 1];
    __builtin_nontemporal_store(bflo(u0) * inv0, pp + kt * 16);
    __builtin_nontemporal_store(bfhi(u0) * inv1, pp + L_ + kt * 16);
    __builtin_nontemporal_store(bflo(u1) * inv2, pp + 2 * L_ + kt * 16);
    __builtin_nontemporal_store(bfhi(u1) * inv3, pp + 3 * L_ + kt * 16);
  }
}

// ---------------- Kernel 2: O = P @ V ----------------
// (unchanged from round 3: ~85us, at the 536MB P-read floor)
__global__ __launch_bounds__(512, 2) void pv_kernel(
    const float* __restrict__ Pg, const float* __restrict__ Vg,
    float* __restrict__ Og) {
  const int tid = threadIdx.x;
  const int w = tid >> 6, lane = tid & 63;
  const int g = lane >> 4, ln = lane & 15;

  const int nq = L_ / 128;  // 16
  const int blk = blockIdx.x;
  const int q0 = (blk % nq) * 128;
  const int bh = blk / nq;

  const float* p = Pg + (size_t)bh * L_ * L_;
  const float* v = Vg + (size_t)bh * L_ * D_;
  float* o = Og + (size_t)bh * L_ * D_;

  __shared__ short vt_lds[2][64 * 64];  // VT[d][k] bf16 (packed pairs), swizzled

  f32x4 acc[4];
#pragma unroll
  for (int n = 0; n < 4; ++n) acc[n] = f32x4{0.f, 0.f, 0.f, 0.f};

  const float* prp = p + (size_t)(q0 + w * 16 + ln) * L_;
  const int kp = tid & 31;
  const int d0 = (tid >> 5) * 4;

#define STAGE_V(buf, kt)                                                        \
  {                                                                             \
    const float* vr0 = v + (size_t)((kt) * 64 + kp * 2) * D_ + d0;              \
    float4 f0 = *(const float4*)vr0;                                            \
    float4 f1 = *(const float4*)(vr0 + D_);                                     \
    unsigned pkx0 = pk2(f0.x, f1.x), pkx1 = pk2(f0.y, f1.y);                    \
    unsigned pkx2 = pk2(f0.z, f1.z), pkx3 = pk2(f0.w, f1.w);                    \
    *(unsigned*)((char*)vt_lds[buf] + (d0 + 0) * 128 + ((kp * 4) ^ (((d0 + 0) & 7) << 4))) = pkx0; \
    *(unsigned*)((char*)vt_lds[buf] + (d0 + 1) * 128 + ((kp * 4) ^ (((d0 + 1) & 7) << 4))) = pkx1; \
    *(unsigned*)((char*)vt_lds[buf] + (d0 + 2) * 128 + ((kp * 4) ^ (((d0 + 2) & 7) << 4))) = pkx2; \
    *(unsigned*)((char*)vt_lds[buf] + (d0 + 3) * 128 + ((kp * 4) ^ (((d0 + 3) & 7) << 4))) = pkx3; \
  }

  float4 pf0, pf1, pf2, pf3;
#define LOAD_P(kt)                                                \
  {                                                               \
    const float* src = prp + (kt) * 64;                           \
    pf0 = *(const float4*)(src + g * 8);                          \
    pf1 = *(const float4*)(src + g * 8 + 4);                      \
    pf2 = *(const float4*)(src + 32 + g * 8);                     \
    pf3 = *(const float4*)(src + 32 + g * 8 + 4);                 \
  }

  STAGE_V(0, 0)
  LOAD_P(0)
  __syncthreads();

  for (int kt = 0; kt < 32; ++kt) {
    const int cur = kt & 1;
    bf16x8 pa0, pa1;
    pa0[0] = f2bf(pf0.x); pa0[1] = f2bf(pf0.y); pa0[2] = f2bf(pf0.z); pa0[3] = f2bf(pf0.w);
    pa0[4] = f2bf(pf1.x); pa0[5] = f2bf(pf1.y); pa0[6] = f2bf(pf1.z); pa0[7] = f2bf(pf1.w);
    pa1[0] = f2bf(pf2.x); pa1[1] = f2bf(pf2.y); pa1[2] = f2bf(pf2.z); pa1[3] = f2bf(pf2.w);
    pa1[4] = f2bf(pf3.x); pa1[5] = f2bf(pf3.y); pa1[6] = f2bf(pf3.z); pa1[7] = f2bf(pf3.w);
    if (kt < 31) {
      STAGE_V(cur ^ 1, kt + 1)
      LOAD_P(kt + 1)
    }
#pragma unroll
    for (int n = 0; n < 4; ++n) {
      const int vrow = n * 16 + ln;
      const int swz = (vrow & 7) << 4;
      bf16x8 bf0 = *(const bf16x8*)((const char*)vt_lds[cur] + vrow * 128 + ((g * 16) ^ swz));
      bf16x8 bf1 = *(const bf16x8*)((const char*)vt_lds[cur] + vrow * 128 + ((64 + g * 16) ^ swz));
      acc[n] = __builtin_amdgcn_mfma_f32_16x16x32_bf16(pa0, bf0, acc[n], 0, 0, 0);
      acc[n] = __builtin_amdgcn_mfma_f32_16x16x32_bf16(pa1, bf1, acc[n], 0, 0, 0);
    }
    __syncthreads();
  }
  const int orow = q0 + w * 16 + g * 4;
#pragma unroll
  for (int n = 0; n < 4; ++n)
#pragma unroll
    for (int r = 0; r < 4; ++r)
      __builtin_nontemporal_store(acc[n][r], o + (size_t)(orow + r) * D_ + n * 16 + ln);
}

extern "C" void kernel_launch(void* const* d_in, const int* in_sizes, int n_in,
                              void* d_out, int out_size, void* d_ws, size_t ws_size,
                              hipStream_t stream) {
  const float* q = (const float*)d_in[0];
  const float* k = (const float*)d_in[1];
  const float* v = (const float*)d_in[2];
  const float* mask = (const float*)d_in[3];
  float* out = (float*)d_out;                      // [B,H,L,D]
  float* score = out + (size_t)B_ * H_ * L_ * D_;  // [B,H,L,L]

  const size_t kp_bytes = (size_t)B_ * H_ * L_ * D_ * sizeof(short);  // 8 MB
  if (ws_size >= kp_bytes) {
    short* kp = (short*)d_ws;
    convert_k_kernel<<<2048, 256, 0, stream>>>(k, kp);
    qk_softmax_kernel<true><<<B_ * H_ * (L_ / 16), 512, 0, stream>>>(q, k, kp, mask, score);
  } else {
    qk_softmax_kernel<false><<<B_ * H_ * (L_ / 16), 512, 0, stream>>>(q, k, nullptr, mask, score);
  }
  pv_kernel<<<B_ * H_ * (L_ / 128), 512, 0, stream>>>(score, v, out);
}

// Round 7
// 270.949 us; speedup vs baseline: 2.9718x; 1.2190x over previous
//
#include <hip/hip_runtime.h>

typedef __attribute__((ext_vector_type(8))) short bf16x8;
typedef __attribute__((ext_vector_type(4))) float f32x4;
typedef __attribute__((ext_vector_type(4))) unsigned u32x4;

#define DEV static __device__ __forceinline__

constexpr int B_ = 2, H_ = 16, L_ = 2048, D_ = 64;
constexpr float SCALE = 0.125f;  // 1/sqrt(64)

DEV short f2bf(float f) {
  unsigned u = __builtin_bit_cast(unsigned, f);
  u += 0x7fffu + ((u >> 16) & 1u);  // RNE
  return (short)(u >> 16);
}
DEV unsigned pk2(float lo, float hi) {
  return (unsigned)(unsigned short)f2bf(lo) | ((unsigned)(unsigned short)f2bf(hi) << 16);
}
DEV float bflo(unsigned u) { return __builtin_bit_cast(float, u << 16); }
DEV float bfhi(unsigned u) { return __builtin_bit_cast(float, u & 0xffff0000u); }

DEV bf16x8 frag_from(const float* src) {  // 8 consecutive f32 -> bf16x8
  float4 f0 = *(const float4*)src;
  float4 f1 = *(const float4*)(src + 4);
  bf16x8 r;
  r[0] = f2bf(f0.x); r[1] = f2bf(f0.y); r[2] = f2bf(f0.z); r[3] = f2bf(f0.w);
  r[4] = f2bf(f1.x); r[5] = f2bf(f1.y); r[6] = f2bf(f1.z); r[7] = f2bf(f1.w);
  return r;
}

// ---------------- Pre-pass 1: K (f32) -> fragment-linear bf16 ----------------
// Kp (bf16x8 units): [bh][ktile 0..127][half 0..1][lane]; lane=g*16+ln holds
// K[bh][ktile*16+ln][half*32+g*8 .. +8).
__global__ __launch_bounds__(256) void convert_k_kernel(
    const float* __restrict__ Kg, short* __restrict__ Kp) {
  const int tid = threadIdx.x;
  const int lane = tid & 63, half = (tid >> 6) & 1, sub = tid >> 7;
  const int blk = blockIdx.x;                   // 2048 blocks
  const int bh = blk >> 6;                      // 32
  const int ktile = (((blk & 63) << 1) | sub);  // 0..127
  const int g = lane >> 4, ln = lane & 15;
  const float* src = Kg + ((size_t)bh * L_ + ktile * 16 + ln) * D_ + half * 32 + g * 8;
  bf16x8 f = frag_from(src);
  *(bf16x8*)(Kp + ((((size_t)(bh * 128 + ktile)) * 2 + half) * 64 + lane) * 8) = f;
}

// ---------------- Pre-pass 2: V (f32) -> transposed bf16 Vt[bh][64][2048] ----
__global__ __launch_bounds__(256) void convert_vt_kernel(
    const float* __restrict__ Vg, short* __restrict__ Vt) {
  const int tid = threadIdx.x;
  const int d = tid & 63, s = tid >> 6;         // d-col, k-segment
  const int bh = blockIdx.x >> 3, kc = blockIdx.x & 7;
  const float* src = Vg + (size_t)bh * L_ * D_ + (size_t)(kc * 256 + s * 64) * D_ + d;
  short* dst = Vt + (size_t)bh * D_ * L_ + (size_t)d * L_ + kc * 256 + s * 64;
#pragma unroll
  for (int i0 = 0; i0 < 8; ++i0) {
    bf16x8 r;
#pragma unroll
    for (int i = 0; i < 8; ++i) r[i] = f2bf(src[(i0 * 8 + i) * D_]);
    *(bf16x8*)(dst + i0 * 8) = r;
  }
}

// ---- V^T chunk staging into LDS: [64 d][256 k] bf16, byte ^= ((d&7)<<4) ----
DEV void stage_pre(short* dst, const short* vtsrc, int c, int tid) {
  const int d = tid >> 3, ks = tid & 7;
  const short* src = vtsrc + (size_t)d * L_ + c * 256 + ks * 32;
  bf16x8 v0 = *(const bf16x8*)(src + 0);
  bf16x8 v1 = *(const bf16x8*)(src + 8);
  bf16x8 v2 = *(const bf16x8*)(src + 16);
  bf16x8 v3 = *(const bf16x8*)(src + 24);
  char* row = (char*)dst + d * 512;
  const int swz = (d & 7) << 4;
  *(bf16x8*)(row + ((ks * 64 + 0) ^ swz)) = v0;
  *(bf16x8*)(row + ((ks * 64 + 16) ^ swz)) = v1;
  *(bf16x8*)(row + ((ks * 64 + 32) ^ swz)) = v2;
  *(bf16x8*)(row + ((ks * 64 + 48) ^ swz)) = v3;
}
DEV void stage_f32(short* dst, const float* vsrc, int c, int tid) {
  const int kp_ = tid & 127, dh = (tid >> 7) * 16;
  const float* r0 = vsrc + (size_t)(c * 256 + kp_ * 2) * D_ + dh;
  const float* r1 = r0 + D_;
  char* base = (char*)dst;
#pragma unroll
  for (int i = 0; i < 4; ++i) {
    float4 a = *(const float4*)(r0 + i * 4);
    float4 b = *(const float4*)(r1 + i * 4);
    unsigned p0 = pk2(a.x, b.x), p1 = pk2(a.y, b.y), p2 = pk2(a.z, b.z), p3 = pk2(a.w, b.w);
    const int dd = dh + i * 4;
    *(unsigned*)(base + (dd + 0) * 512 + ((kp_ * 4) ^ (((dd + 0) & 7) << 4))) = p0;
    *(unsigned*)(base + (dd + 1) * 512 + ((kp_ * 4) ^ (((dd + 1) & 7) << 4))) = p1;
    *(unsigned*)(base + (dd + 2) * 512 + ((kp_ * 4) ^ (((dd + 2) & 7) << 4))) = p2;
    *(unsigned*)(base + (dd + 3) * 512 + ((kp_ * 4) ^ (((dd + 3) & 7) << 4))) = p3;
  }
}

// ---------------- Fused kernel ----------------
// 512 threads (8 waves), q-tile 16 rows. Swapped QK^T: mfma(K,Q) -> lane (g,ln)
// holds row ln, k-cols tile*16+g*4+r; wave w owns tiles w+8j (j=0..15).
// PV: shared V^T chunks of 256 k; in chunk c wave w contributes its tiles
// c*16+w and c*16+w+8 (its pkv[4c..4c+3] ARE the A-fragment); 8-way O reduce.
template <bool USEPRE>
__global__ __launch_bounds__(512, 4) void attn_fused(
    const float* __restrict__ Qg, const float* __restrict__ Kg,
    const short* __restrict__ Kp, const float* __restrict__ Vg,
    const short* __restrict__ Vtg, const float* __restrict__ Mg,
    float* __restrict__ Pg, float* __restrict__ Og) {
  const int tid = threadIdx.x;
  const int w = tid >> 6, lane = tid & 63;
  const int g = lane >> 4, ln = lane & 15;

  // XCD-chunked swizzle: 4096 blocks = 8 XCDs x 512; same-bh blocks per XCD.
  const int bid = blockIdx.x;
  const int wg = (bid & 7) * 512 + (bid >> 3);
  const int q0 = (wg & 127) << 4;
  const int bh = wg >> 7;
  const int b = bh >> 4;  // H_=16

  __shared__ short vt[2][64 * 256];  // 2 x 32KB V^T chunk double-buffer
  __shared__ float red[8][16];

  const float* qp = Qg + (size_t)bh * L_ * D_;
  const float* mrow = Mg + (size_t)b * L_ * L_ + (size_t)(q0 + ln) * L_;
  float* prow = Pg + (size_t)bh * L_ * L_ + (size_t)(q0 + ln) * L_;

  bf16x8 qf0 = frag_from(qp + (size_t)(q0 + ln) * D_ + g * 8);
  bf16x8 qf1 = frag_from(qp + (size_t)(q0 + ln) * D_ + 32 + g * 8);

  unsigned pkv[32];
  float mx = -1e30f;
  const bf16x8* kpb = (const bf16x8*)Kp + ((size_t)bh * 128 + w) * 128 + lane;

#pragma unroll
  for (int j = 0; j < 16; ++j) {
    bf16x8 k0, k1;
    if (USEPRE) {
      k0 = kpb[j * 1024];
      k1 = kpb[j * 1024 + 64];
    } else {
      const float* kr = Kg + (size_t)bh * L_ * D_ + (size_t)((w + 8 * j) * 16 + ln) * D_;
      k0 = frag_from(kr + g * 8);
      k1 = frag_from(kr + 32 + g * 8);
    }
    f32x4 acc{0.f, 0.f, 0.f, 0.f};
    acc = __builtin_amdgcn_mfma_f32_16x16x32_bf16(k0, qf0, acc, 0, 0, 0);
    acc = __builtin_amdgcn_mfma_f32_16x16x32_bf16(k1, qf1, acc, 0, 0, 0);
    float4 mk = *(const float4*)(mrow + (w + 8 * j) * 16 + g * 4);
    float l0 = acc[0] * SCALE * mk.x;
    float l1 = acc[1] * SCALE * mk.y;
    float l2 = acc[2] * SCALE * mk.z;
    float l3 = acc[3] * SCALE * mk.w;
    mx = fmaxf(mx, fmaxf(fmaxf(l0, l1), fmaxf(l2, l3)));
    pkv[2 * j] = pk2(l0, l1);
    pkv[2 * j + 1] = pk2(l2, l3);
  }

  // issue chunk-0 V^T staging early; softmax hides its latency
  if (USEPRE) stage_pre(vt[0], Vtg + (size_t)bh * D_ * L_, 0, tid);
  else stage_f32(vt[0], Vg + (size_t)bh * L_ * D_, 0, tid);

  // ---- softmax (row ln per lane) ----
  mx = fmaxf(mx, __shfl_xor(mx, 16));
  mx = fmaxf(mx, __shfl_xor(mx, 32));
  if (lane < 16) red[w][ln] = mx;
  __syncthreads();
  {
    float t = red[0][ln];
#pragma unroll
    for (int ww = 1; ww < 8; ++ww) t = fmaxf(t, red[ww][ln]);
    mx = t;
  }
  float sm = 0.f;
#pragma unroll
  for (int j = 0; j < 16; ++j) {
    float e0 = __expf(bflo(pkv[2 * j]) - mx);
    float e1 = __expf(bfhi(pkv[2 * j]) - mx);
    float e2 = __expf(bflo(pkv[2 * j + 1]) - mx);
    float e3 = __expf(bfhi(pkv[2 * j + 1]) - mx);
    sm += (e0 + e1) + (e2 + e3);
    pkv[2 * j] = pk2(e0, e1);
    pkv[2 * j + 1] = pk2(e2, e3);
  }
  sm += __shfl_xor(sm, 16);
  sm += __shfl_xor(sm, 32);
  __syncthreads();  // max-phase readers done with red
  if (lane < 16) red[w][ln] = sm;
  __syncthreads();
  float inv;
  {
    float t = red[0][ln];
#pragma unroll
    for (int ww = 1; ww < 8; ++ww) t += red[ww][ln];
    inv = 1.0f / t;
  }

  // ---- write P (nt, f32x4) + repack normalized bf16 (the PV A-frags) ----
#pragma unroll
  for (int j = 0; j < 16; ++j) {
    float n0 = bflo(pkv[2 * j]) * inv, n1 = bfhi(pkv[2 * j]) * inv;
    float n2 = bflo(pkv[2 * j + 1]) * inv, n3 = bfhi(pkv[2 * j + 1]) * inv;
    f32x4 st{n0, n1, n2, n3};
    __builtin_nontemporal_store(st, (f32x4*)(prow + (w + 8 * j) * 16 + g * 4));
    pkv[2 * j] = pk2(n0, n1);
    pkv[2 * j + 1] = pk2(n2, n3);
  }

  // ---- PV chunk loop ----
  f32x4 acc_o[4];
#pragma unroll
  for (int n = 0; n < 4; ++n) acc_o[n] = f32x4{0.f, 0.f, 0.f, 0.f};

  const short* vsrc_pre = Vtg + (size_t)bh * D_ * L_;
  const float* vsrc_f32 = Vg + (size_t)bh * L_ * D_;
  const int boff = w * 32 + g * 8;

#pragma unroll
  for (int c = 0; c < 8; ++c) {
    if (c < 7) {
      if (USEPRE) stage_pre(vt[(c + 1) & 1], vsrc_pre, c + 1, tid);
      else stage_f32(vt[(c + 1) & 1], vsrc_f32, c + 1, tid);
    }
    u32x4 au{pkv[4 * c], pkv[4 * c + 1], pkv[4 * c + 2], pkv[4 * c + 3]};
    bf16x8 pa = __builtin_bit_cast(bf16x8, au);
    const char* buf = (const char*)vt[c & 1];
#pragma unroll
    for (int n = 0; n < 4; ++n) {
      const int d = n * 16 + ln;
      const char* rowp = buf + d * 512;
      const int off = boff ^ ((d & 7) << 4);
      uint2 lo = *(const uint2*)(rowp + off);
      uint2 hi = *(const uint2*)(rowp + off + 256);
      u32x4 bu{lo.x, lo.y, hi.x, hi.y};
      acc_o[n] = __builtin_amdgcn_mfma_f32_16x16x32_bf16(
          pa, __builtin_bit_cast(bf16x8, bu), acc_o[n], 0, 0, 0);
    }
    __syncthreads();
  }

  // ---- 8-way O-partial reduce (alias vt[0] region) + write O ----
  float* red_o = (float*)vt;  // 32 KB
#pragma unroll
  for (int n = 0; n < 4; ++n)
#pragma unroll
    for (int r = 0; r < 4; ++r)
      red_o[(w * 16 + g * 4 + r) * 64 + n * 16 + ln] = acc_o[n][r];
  __syncthreads();
  {
    float* ob = Og + (size_t)bh * L_ * D_ + (size_t)q0 * D_;
    const int row = tid >> 5, dp = (tid & 31) * 2;
    float s0 = 0.f, s1 = 0.f;
#pragma unroll
    for (int ww = 0; ww < 8; ++ww) {
      s0 += red_o[(ww * 16 + row) * 64 + dp];
      s1 += red_o[(ww * 16 + row) * 64 + dp + 1];
    }
    __builtin_nontemporal_store(s0, ob + row * D_ + dp);
    __builtin_nontemporal_store(s1, ob + row * D_ + dp + 1);
  }
}

extern "C" void kernel_launch(void* const* d_in, const int* in_sizes, int n_in,
                              void* d_out, int out_size, void* d_ws, size_t ws_size,
                              hipStream_t stream) {
  const float* q = (const float*)d_in[0];
  const float* k = (const float*)d_in[1];
  const float* v = (const float*)d_in[2];
  const float* mask = (const float*)d_in[3];
  float* out = (float*)d_out;                      // [B,H,L,D]
  float* score = out + (size_t)B_ * H_ * L_ * D_;  // [B,H,L,L]

  const size_t elems = (size_t)B_ * H_ * L_ * D_;  // 4.19M
  const size_t need = elems * 2 * sizeof(short);   // Kp + Vt = 16 MB
  const int nblk = B_ * H_ * (L_ / 16);            // 4096

  if (ws_size >= need) {
    short* kp = (short*)d_ws;
    short* vtg = kp + elems;
    convert_k_kernel<<<2048, 256, 0, stream>>>(k, kp);
    convert_vt_kernel<<<B_ * H_ * 8, 256, 0, stream>>>(v, vtg);
    attn_fused<true><<<nblk, 512, 0, stream>>>(q, k, kp, v, vtg, mask, score, out);
  } else {
    attn_fused<false><<<nblk, 512, 0, stream>>>(q, k, nullptr, v, nullptr, mask, score, out);
  }
}